// Round 1
// baseline (494.196 us; speedup 1.0000x reference)
//
#include <hip/hip_runtime.h>

// Self-attention: x(1,4096,1024) fp32; Q/K/V/O projections + causal softmax attention.
// bf16 MFMA pipeline; workspace usage: 32 MB (Q,K,V head-major bf16 + Y bf16).

#define TSZ 4096
#define DM  1024
#define NH  16
#define DH  64

typedef __bf16 bf16x8 __attribute__((ext_vector_type(8)));
typedef float  f32x4  __attribute__((ext_vector_type(4)));

__device__ __forceinline__ unsigned short f2bf(float x) {
    unsigned int u = __builtin_bit_cast(unsigned int, x);
    u += 0x7fffu + ((u >> 16) & 1u);
    return (unsigned short)(u >> 16);
}

// ---------------- QKV projection: y = x @ W^T + b, bf16 out, head-major ----------------
// grid (8, 32, 3), block 256. Tile 128x128, BK=32. z selects Q/K/V.
__global__ __launch_bounds__(256)
void qkv_kernel(const float* __restrict__ x,
                const float* __restrict__ Wq, const float* __restrict__ bq,
                const float* __restrict__ Wk, const float* __restrict__ bk,
                const float* __restrict__ Wv, const float* __restrict__ bv,
                unsigned short* __restrict__ qw,
                unsigned short* __restrict__ kw,
                unsigned short* __restrict__ vw) {
    const float* W; const float* bias; unsigned short* out; float scale;
    if (blockIdx.z == 0)      { W = Wq; bias = bq; out = qw; scale = 0.125f; } // fold 1/sqrt(64) into Q
    else if (blockIdx.z == 1) { W = Wk; bias = bk; out = kw; scale = 1.0f; }
    else                      { W = Wv; bias = bv; out = vw; scale = 1.0f; }

    __shared__ unsigned short Alds[128][32];
    __shared__ unsigned short Blds[128][32];

    const int tid  = threadIdx.x;
    const int wave = tid >> 6, lane = tid & 63;
    const int wr = (wave >> 1) * 64, wc = (wave & 1) * 64;
    const int row0 = blockIdx.y * 128, col0 = blockIdx.x * 128;

    f32x4 acc[4][4];
#pragma unroll
    for (int m = 0; m < 4; ++m)
#pragma unroll
        for (int n = 0; n < 4; ++n) acc[m][n] = (f32x4){0.f, 0.f, 0.f, 0.f};

    for (int kt = 0; kt < DM; kt += 32) {
#pragma unroll
        for (int i = 0; i < 4; ++i) {
            int idx = tid + i * 256;       // 1024 chunks of 4 elems
            int r = idx >> 3, c = (idx & 7) << 2;
            float4 av = *reinterpret_cast<const float4*>(&x[(size_t)(row0 + r) * DM + kt + c]);
            unsigned int a0 = (unsigned)f2bf(av.x) | ((unsigned)f2bf(av.y) << 16);
            unsigned int a1 = (unsigned)f2bf(av.z) | ((unsigned)f2bf(av.w) << 16);
            *reinterpret_cast<uint2*>(&Alds[r][c]) = make_uint2(a0, a1);
            float4 bv4 = *reinterpret_cast<const float4*>(&W[(size_t)(col0 + r) * DM + kt + c]);
            unsigned int b0 = (unsigned)f2bf(bv4.x) | ((unsigned)f2bf(bv4.y) << 16);
            unsigned int b1 = (unsigned)f2bf(bv4.z) | ((unsigned)f2bf(bv4.w) << 16);
            *reinterpret_cast<uint2*>(&Blds[r][c]) = make_uint2(b0, b1);
        }
        __syncthreads();
        const int ko = (lane >> 4) << 3;
        bf16x8 a[4], b[4];
#pragma unroll
        for (int m = 0; m < 4; ++m)
            a[m] = *reinterpret_cast<const bf16x8*>(&Alds[wr + m * 16 + (lane & 15)][ko]);
#pragma unroll
        for (int n = 0; n < 4; ++n)
            b[n] = *reinterpret_cast<const bf16x8*>(&Blds[wc + n * 16 + (lane & 15)][ko]);
#pragma unroll
        for (int m = 0; m < 4; ++m)
#pragma unroll
            for (int n = 0; n < 4; ++n)
                acc[m][n] = __builtin_amdgcn_mfma_f32_16x16x32_bf16(a[m], b[n], acc[m][n], 0, 0, 0);
        __syncthreads();
    }

#pragma unroll
    for (int n = 0; n < 4; ++n) {
        int col = col0 + wc + n * 16 + (lane & 15);
        float bval = bias[col];
        int hh = col >> 6, dd = col & 63;
#pragma unroll
        for (int m = 0; m < 4; ++m) {
            int rbase = row0 + wr + m * 16 + ((lane >> 4) << 2);
#pragma unroll
            for (int r = 0; r < 4; ++r) {
                float v = (acc[m][n][r] + bval) * scale;
                out[((size_t)hh * TSZ + rbase + r) * DH + dd] = f2bf(v);
            }
        }
    }
}

// ---------------- Flash attention, causal. grid (64 qtiles, 16 heads), block 256 ----------------
__global__ __launch_bounds__(256)
void attn_kernel(const unsigned short* __restrict__ qw,
                 const unsigned short* __restrict__ kw,
                 const unsigned short* __restrict__ vw,
                 unsigned short* __restrict__ yw) {
    const int qt = blockIdx.x, h = blockIdx.y;
    const int tid = threadIdx.x;
    const int w = tid >> 6, lane = tid & 63;

    __shared__ unsigned short Qs[64 * 64];
    __shared__ unsigned short Ks[64 * 64];
    __shared__ unsigned short VTs[64 * 64]; // [d][tk]
    __shared__ float          Ss[64 * 64];
    __shared__ unsigned short Ps[64 * 64];
    __shared__ float mrow[64], lrow[64], srow[64];

    // load Q tile (contiguous 8KB in head-major layout)
    const unsigned short* qsrc = qw + ((size_t)h * TSZ + (size_t)qt * 64) * DH;
#pragma unroll
    for (int i = 0; i < 2; ++i) {
        int idx = tid + i * 256; // 512 chunks of 8 bf16
        *reinterpret_cast<float4*>(&Qs[idx * 8]) = *reinterpret_cast<const float4*>(&qsrc[idx * 8]);
    }
    if (tid < 64) { mrow[tid] = -__builtin_inff(); lrow[tid] = 0.f; }

    f32x4 accO[4];
#pragma unroll
    for (int n = 0; n < 4; ++n) accO[n] = (f32x4){0.f, 0.f, 0.f, 0.f};

    __syncthreads();

    for (int j = 0; j <= qt; ++j) {
        // stage K_j (copy) and V_j (transposed)
        const unsigned short* ksrc = kw + ((size_t)h * TSZ + (size_t)j * 64) * DH;
        const unsigned short* vsrc = vw + ((size_t)h * TSZ + (size_t)j * 64) * DH;
#pragma unroll
        for (int i = 0; i < 2; ++i) {
            int idx = tid + i * 256;
            *reinterpret_cast<float4*>(&Ks[idx * 8]) = *reinterpret_cast<const float4*>(&ksrc[idx * 8]);
        }
#pragma unroll
        for (int i = 0; i < 2; ++i) {
            int idx = tid + i * 256;   // 512 chunks: tk = idx>>3, d0 = (idx&7)*8
            int tk = idx >> 3, d0 = (idx & 7) << 3;
            uint4 vv = *reinterpret_cast<const uint4*>(&vsrc[tk * DH + d0]);
            VTs[(d0 + 0) * 64 + tk] = (unsigned short)(vv.x & 0xffff);
            VTs[(d0 + 1) * 64 + tk] = (unsigned short)(vv.x >> 16);
            VTs[(d0 + 2) * 64 + tk] = (unsigned short)(vv.y & 0xffff);
            VTs[(d0 + 3) * 64 + tk] = (unsigned short)(vv.y >> 16);
            VTs[(d0 + 4) * 64 + tk] = (unsigned short)(vv.z & 0xffff);
            VTs[(d0 + 5) * 64 + tk] = (unsigned short)(vv.z >> 16);
            VTs[(d0 + 6) * 64 + tk] = (unsigned short)(vv.w & 0xffff);
            VTs[(d0 + 7) * 64 + tk] = (unsigned short)(vv.w >> 16);
        }
        __syncthreads();

        // S strip = Q_strip @ K_j^T   (wave w owns q rows [w*16, w*16+16))
        f32x4 sacc[4];
#pragma unroll
        for (int n = 0; n < 4; ++n) sacc[n] = (f32x4){0.f, 0.f, 0.f, 0.f};
#pragma unroll
        for (int kk = 0; kk < 2; ++kk) {
            bf16x8 aq = *reinterpret_cast<const bf16x8*>(&Qs[(w * 16 + (lane & 15)) * 64 + kk * 32 + ((lane >> 4) << 3)]);
#pragma unroll
            for (int n = 0; n < 4; ++n) {
                bf16x8 bk = *reinterpret_cast<const bf16x8*>(&Ks[(n * 16 + (lane & 15)) * 64 + kk * 32 + ((lane >> 4) << 3)]);
                sacc[n] = __builtin_amdgcn_mfma_f32_16x16x32_bf16(aq, bk, sacc[n], 0, 0, 0);
            }
        }
        // causal mask + store S
        const int qg = qt * 64 + w * 16 + ((lane >> 4) << 2);
#pragma unroll
        for (int n = 0; n < 4; ++n) {
            int kg = j * 64 + n * 16 + (lane & 15);
#pragma unroll
            for (int r = 0; r < 4; ++r) {
                float s = sacc[n][r];
                if (kg > qg + r) s = -__builtin_inff();
                Ss[(w * 16 + ((lane >> 4) << 2) + r) * 64 + n * 16 + (lane & 15)] = s;
            }
        }
        __syncthreads();

        // online softmax: 4 threads per row, 16 cols each
        {
            int row = tid >> 2, part = tid & 3;
            float mx = -__builtin_inff();
#pragma unroll
            for (int c = 0; c < 16; ++c) mx = fmaxf(mx, Ss[row * 64 + part * 16 + c]);
            mx = fmaxf(mx, __shfl_xor(mx, 1));
            mx = fmaxf(mx, __shfl_xor(mx, 2));
            float mold = mrow[row];
            float mnew = fmaxf(mold, mx);
            float sc = __expf(mold - mnew);
            float sum = 0.f;
#pragma unroll
            for (int c = 0; c < 16; ++c) {
                float p = __expf(Ss[row * 64 + part * 16 + c] - mnew);
                sum += p;
                Ps[row * 64 + part * 16 + c] = f2bf(p);
            }
            sum += __shfl_xor(sum, 1);
            sum += __shfl_xor(sum, 2);
            if (part == 0) { mrow[row] = mnew; lrow[row] = lrow[row] * sc + sum; srow[row] = sc; }
        }
        __syncthreads();

        // rescale accumulator, then O += P @ V
#pragma unroll
        for (int r = 0; r < 4; ++r) {
            float f = srow[w * 16 + ((lane >> 4) << 2) + r];
#pragma unroll
            for (int n = 0; n < 4; ++n) accO[n][r] *= f;
        }
#pragma unroll
        for (int kk = 0; kk < 2; ++kk) {
            bf16x8 ap = *reinterpret_cast<const bf16x8*>(&Ps[(w * 16 + (lane & 15)) * 64 + kk * 32 + ((lane >> 4) << 3)]);
#pragma unroll
            for (int n = 0; n < 4; ++n) {
                bf16x8 bv = *reinterpret_cast<const bf16x8*>(&VTs[(n * 16 + (lane & 15)) * 64 + kk * 32 + ((lane >> 4) << 3)]);
                accO[n] = __builtin_amdgcn_mfma_f32_16x16x32_bf16(ap, bv, accO[n], 0, 0, 0);
            }
        }
        __syncthreads();
    }

    // epilogue: O /= l, write Y (row-major T x 1024)
#pragma unroll
    for (int r = 0; r < 4; ++r) {
        int qrow = qt * 64 + w * 16 + ((lane >> 4) << 2) + r;
        float inv = 1.0f / lrow[w * 16 + ((lane >> 4) << 2) + r];
#pragma unroll
        for (int n = 0; n < 4; ++n) {
            int d = n * 16 + (lane & 15);
            yw[(size_t)qrow * DM + h * DH + d] = f2bf(accO[n][r] * inv);
        }
    }
}

// ---------------- O projection: out = Y @ Wo^T + bo (fp32 out) ----------------
__global__ __launch_bounds__(256)
void oproj_kernel(const unsigned short* __restrict__ y,
                  const float* __restrict__ Wo, const float* __restrict__ bo,
                  float* __restrict__ out) {
    __shared__ unsigned short Alds[128][32];
    __shared__ unsigned short Blds[128][32];

    const int tid  = threadIdx.x;
    const int wave = tid >> 6, lane = tid & 63;
    const int wr = (wave >> 1) * 64, wc = (wave & 1) * 64;
    const int row0 = blockIdx.y * 128, col0 = blockIdx.x * 128;

    f32x4 acc[4][4];
#pragma unroll
    for (int m = 0; m < 4; ++m)
#pragma unroll
        for (int n = 0; n < 4; ++n) acc[m][n] = (f32x4){0.f, 0.f, 0.f, 0.f};

    for (int kt = 0; kt < DM; kt += 32) {
#pragma unroll
        for (int i = 0; i < 4; ++i) {
            int idx = tid + i * 256;
            int r = idx >> 3, c = (idx & 7) << 2;
            *reinterpret_cast<uint2*>(&Alds[r][c]) =
                *reinterpret_cast<const uint2*>(&y[(size_t)(row0 + r) * DM + kt + c]);
            float4 bv4 = *reinterpret_cast<const float4*>(&Wo[(size_t)(col0 + r) * DM + kt + c]);
            unsigned int b0 = (unsigned)f2bf(bv4.x) | ((unsigned)f2bf(bv4.y) << 16);
            unsigned int b1 = (unsigned)f2bf(bv4.z) | ((unsigned)f2bf(bv4.w) << 16);
            *reinterpret_cast<uint2*>(&Blds[r][c]) = make_uint2(b0, b1);
        }
        __syncthreads();
        const int ko = (lane >> 4) << 3;
        bf16x8 a[4], b[4];
#pragma unroll
        for (int m = 0; m < 4; ++m)
            a[m] = *reinterpret_cast<const bf16x8*>(&Alds[wr + m * 16 + (lane & 15)][ko]);
#pragma unroll
        for (int n = 0; n < 4; ++n)
            b[n] = *reinterpret_cast<const bf16x8*>(&Blds[wc + n * 16 + (lane & 15)][ko]);
#pragma unroll
        for (int m = 0; m < 4; ++m)
#pragma unroll
            for (int n = 0; n < 4; ++n)
                acc[m][n] = __builtin_amdgcn_mfma_f32_16x16x32_bf16(a[m], b[n], acc[m][n], 0, 0, 0);
        __syncthreads();
    }

#pragma unroll
    for (int n = 0; n < 4; ++n) {
        int col = col0 + wc + n * 16 + (lane & 15);
        float bval = bo[col];
#pragma unroll
        for (int m = 0; m < 4; ++m) {
            int rbase = row0 + wr + m * 16 + ((lane >> 4) << 2);
#pragma unroll
            for (int r = 0; r < 4; ++r)
                out[(size_t)(rbase + r) * DM + col] = acc[m][n][r] + bval;
        }
    }
}

extern "C" void kernel_launch(void* const* d_in, const int* in_sizes, int n_in,
                              void* d_out, int out_size, void* d_ws, size_t ws_size,
                              hipStream_t stream) {
    const float* x  = (const float*)d_in[0];
    const float* Wq = (const float*)d_in[1];
    const float* bq = (const float*)d_in[2];
    const float* Wk = (const float*)d_in[3];
    const float* bk = (const float*)d_in[4];
    const float* Wv = (const float*)d_in[5];
    const float* bv = (const float*)d_in[6];
    const float* Wo = (const float*)d_in[7];
    const float* bo = (const float*)d_in[8];
    float* out = (float*)d_out;

    // workspace: Q,K,V head-major bf16 (8MB each) + Y row-major bf16 (8MB) = 32MB
    unsigned short* qw = (unsigned short*)d_ws;
    unsigned short* kw = qw + (size_t)TSZ * DM;
    unsigned short* vw = kw + (size_t)TSZ * DM;
    unsigned short* yw = vw + (size_t)TSZ * DM;

    qkv_kernel<<<dim3(8, 32, 3), 256, 0, stream>>>(x, Wq, bq, Wk, bk, Wv, bv, qw, kw, vw);
    attn_kernel<<<dim3(64, 16), 256, 0, stream>>>(qw, kw, vw, yw);
    oproj_kernel<<<dim3(8, 32), 256, 0, stream>>>(yw, Wo, bo, out);
}

// Round 2
// 355.106 us; speedup vs baseline: 1.3917x; 1.3917x over previous
//
#include <hip/hip_runtime.h>

// Self-attention: x(1,4096,1024) fp32. bf16 MFMA pipeline.
// ws: qw[h][t][d], kw[h][t][d], vtw[h][d][t], yw[t][dm]  (8MB each, 32MB)

#define TSZ 4096
#define DM  1024
#define NH  16
#define DH  64

typedef __bf16 bf16x8 __attribute__((ext_vector_type(8)));
typedef float  f32x4  __attribute__((ext_vector_type(4)));

__device__ __forceinline__ unsigned short f2bf(float x) {
    unsigned int u = __builtin_bit_cast(unsigned int, x);
    u += 0x7fffu + ((u >> 16) & 1u);
    return (unsigned short)(u >> 16);
}

__device__ __forceinline__ uint4 pack8(const float4 a, const float4 b) {
    uint4 r;
    r.x = (unsigned)f2bf(a.x) | ((unsigned)f2bf(a.y) << 16);
    r.y = (unsigned)f2bf(a.z) | ((unsigned)f2bf(a.w) << 16);
    r.z = (unsigned)f2bf(b.x) | ((unsigned)f2bf(b.y) << 16);
    r.w = (unsigned)f2bf(b.z) | ((unsigned)f2bf(b.w) << 16);
    return r;
}

// XOR-swizzled short-index into a [rows][64-short] tile (128B row stride).
// cb = column BYTE offset (0..127, multiple of 2; 16B accesses use cb%16==0).
__device__ __forceinline__ int sw(int row, int cb) {
    return row * 64 + ((cb ^ ((row & 7) << 4)) >> 1);
}

// ---------------- QKV projection. grid (8,32,3), block 256. Tile 128x128, BK=64 ----------------
// z=0: Q (scaled 1/8) -> qw[h][t][d]; z=1: K -> kw[h][t][d]; z=2: V -> vtw[h][d][t] (transposed)
__global__ __launch_bounds__(256)
void qkv_kernel(const float* __restrict__ x,
                const float* __restrict__ Wq, const float* __restrict__ bq,
                const float* __restrict__ Wk, const float* __restrict__ bk,
                const float* __restrict__ Wv, const float* __restrict__ bv,
                unsigned short* __restrict__ qw,
                unsigned short* __restrict__ kw,
                unsigned short* __restrict__ vtw) {
    const int z = blockIdx.z;
    const float* W; const float* bias; unsigned short* outp; float scale = 1.0f;
    if (z == 0)      { W = Wq; bias = bq; outp = qw; scale = 0.125f; }
    else if (z == 1) { W = Wk; bias = bk; outp = kw; }
    else             { W = Wv; bias = bv; outp = vtw; }

    __shared__ unsigned short Al[128 * 64];
    __shared__ unsigned short Bl[128 * 64];

    const int tid = threadIdx.x;
    const int wv = tid >> 6, lane = tid & 63, g = lane >> 4, l15 = lane & 15;
    const int wr = (wv >> 1) * 64, wc = (wv & 1) * 64;
    const int row0 = blockIdx.y * 128, col0 = blockIdx.x * 128;

    f32x4 acc[4][4];
#pragma unroll
    for (int m = 0; m < 4; ++m)
#pragma unroll
        for (int n = 0; n < 4; ++n) acc[m][n] = (f32x4){0.f, 0.f, 0.f, 0.f};

    for (int kt = 0; kt < DM; kt += 64) {
#pragma unroll
        for (int i = 0; i < 4; ++i) {
            int idx = tid + i * 256;            // 1024 chunks of 8 shorts
            int r = idx >> 3, c8 = idx & 7;
            const float* pa = &x[(size_t)(row0 + r) * DM + kt + c8 * 8];
            float4 a0 = *reinterpret_cast<const float4*>(pa);
            float4 a1 = *reinterpret_cast<const float4*>(pa + 4);
            *reinterpret_cast<uint4*>(&Al[sw(r, c8 * 16)]) = pack8(a0, a1);
            const float* pb = &W[(size_t)(col0 + r) * DM + kt + c8 * 8];
            float4 b0 = *reinterpret_cast<const float4*>(pb);
            float4 b1 = *reinterpret_cast<const float4*>(pb + 4);
            *reinterpret_cast<uint4*>(&Bl[sw(r, c8 * 16)]) = pack8(b0, b1);
        }
        __syncthreads();
#pragma unroll
        for (int kk = 0; kk < 2; ++kk) {
            bf16x8 a[4], b[4];
#pragma unroll
            for (int m = 0; m < 4; ++m)
                a[m] = *reinterpret_cast<const bf16x8*>(&Al[sw(wr + m * 16 + l15, kk * 64 + 16 * g)]);
#pragma unroll
            for (int n = 0; n < 4; ++n)
                b[n] = *reinterpret_cast<const bf16x8*>(&Bl[sw(wc + n * 16 + l15, kk * 64 + 16 * g)]);
            if (z == 2) {
#pragma unroll
                for (int m = 0; m < 4; ++m)
#pragma unroll
                    for (int n = 0; n < 4; ++n)
                        acc[m][n] = __builtin_amdgcn_mfma_f32_16x16x32_bf16(b[n], a[m], acc[m][n], 0, 0, 0);
            } else {
#pragma unroll
                for (int m = 0; m < 4; ++m)
#pragma unroll
                    for (int n = 0; n < 4; ++n)
                        acc[m][n] = __builtin_amdgcn_mfma_f32_16x16x32_bf16(a[m], b[n], acc[m][n], 0, 0, 0);
            }
        }
        __syncthreads();
    }

    if (z == 2) {
        // D rows -> out channel, D cols (l15) -> t. Write V^T [ch][t] coalesced.
#pragma unroll
        for (int n = 0; n < 4; ++n)
#pragma unroll
            for (int r = 0; r < 4; ++r) {
                int ch = col0 + wc + n * 16 + 4 * g + r;
                float bval = bias[ch];
#pragma unroll
                for (int m = 0; m < 4; ++m) {
                    int t = row0 + wr + m * 16 + l15;
                    outp[(size_t)ch * TSZ + t] = f2bf(acc[m][n][r] + bval);
                }
            }
    } else {
#pragma unroll
        for (int n = 0; n < 4; ++n) {
            int col = col0 + wc + n * 16 + l15;
            float bval = bias[col];
            int hh = col >> 6, dd = col & 63;
#pragma unroll
            for (int m = 0; m < 4; ++m) {
                int rbase = row0 + wr + m * 16 + 4 * g;
#pragma unroll
                for (int r = 0; r < 4; ++r)
                    outp[((size_t)hh * TSZ + rbase + r) * DH + dd] = f2bf((acc[m][n][r] + bval) * scale);
            }
        }
    }
}

// ---------------- Flash attention, causal. grid (32, 16), block 256 ----------------
// Block handles qtiles bx and 63-bx (uniform 65 k-tiles). 1 barrier per k-tile.
__global__ __launch_bounds__(256)
void attn_kernel(const unsigned short* __restrict__ qw,
                 const unsigned short* __restrict__ kw,
                 const unsigned short* __restrict__ vtw,
                 unsigned short* __restrict__ yw) {
    __shared__ unsigned short Qs[64 * 64];
    __shared__ unsigned short Ks[2][64 * 64];
    __shared__ unsigned short Vs[2][64 * 64];   // V^T tile: [d][t]
    __shared__ unsigned short Ps[64 * 64];

    const int h = blockIdx.y;
    const int tid = threadIdx.x;
    const int wv = tid >> 6, lane = tid & 63, g = lane >> 4, l15 = lane & 15;

    const unsigned short* qbase = qw + (size_t)h * TSZ * DH;
    const unsigned short* kbase = kw + (size_t)h * TSZ * DH;
    const unsigned short* vbase = vtw + (size_t)h * DH * TSZ;

    for (int half = 0; half < 2; ++half) {
        const int qt = (half == 0) ? (int)blockIdx.x : 63 - (int)blockIdx.x;

        // stage Q tile and K/V tile j=0
        {
            const unsigned short* qsrc = qbase + (size_t)qt * 64 * DH;
#pragma unroll
            for (int i = 0; i < 2; ++i) {
                int c = tid + i * 256;
                int r = c >> 3, c8 = c & 7;
                *reinterpret_cast<uint4*>(&Qs[sw(r, c8 * 16)]) =
                    *reinterpret_cast<const uint4*>(qsrc + c * 8);
                *reinterpret_cast<uint4*>(&Ks[0][sw(r, c8 * 16)]) =
                    *reinterpret_cast<const uint4*>(kbase + c * 8);
                *reinterpret_cast<uint4*>(&Vs[0][sw(r, c8 * 16)]) =
                    *reinterpret_cast<const uint4*>(vbase + (size_t)r * TSZ + c8 * 8);
            }
        }
        __syncthreads();

        bf16x8 aq[2];
        aq[0] = *reinterpret_cast<const bf16x8*>(&Qs[sw(wv * 16 + l15, 16 * g)]);
        aq[1] = *reinterpret_cast<const bf16x8*>(&Qs[sw(wv * 16 + l15, 64 + 16 * g)]);

        float m_st[4], l_st[4];
        f32x4 accO[4];
#pragma unroll
        for (int r = 0; r < 4; ++r) { m_st[r] = -__builtin_inff(); l_st[r] = 0.f; }
#pragma unroll
        for (int n = 0; n < 4; ++n) accO[n] = (f32x4){0.f, 0.f, 0.f, 0.f};

        for (int j = 0; j <= qt; ++j) {
            const int cur = j & 1;
            const bool pf = (j < qt);
            uint4 pk0, pk1, pv0, pv1;
            if (pf) {   // issue next-tile loads early (latency hides under QK+softmax)
                const unsigned short* ks = kbase + (size_t)(j + 1) * 64 * DH;
                const unsigned short* vs = vbase + (size_t)(j + 1) * 64;
                int c0 = tid, c1 = tid + 256;
                pk0 = *reinterpret_cast<const uint4*>(ks + c0 * 8);
                pk1 = *reinterpret_cast<const uint4*>(ks + c1 * 8);
                pv0 = *reinterpret_cast<const uint4*>(vs + (size_t)(c0 >> 3) * TSZ + (c0 & 7) * 8);
                pv1 = *reinterpret_cast<const uint4*>(vs + (size_t)(c1 >> 3) * TSZ + (c1 & 7) * 8);
            }

            // S = Q K^T
            f32x4 sacc[4];
#pragma unroll
            for (int n = 0; n < 4; ++n) sacc[n] = (f32x4){0.f, 0.f, 0.f, 0.f};
#pragma unroll
            for (int kk = 0; kk < 2; ++kk) {
#pragma unroll
                for (int n = 0; n < 4; ++n) {
                    bf16x8 bk = *reinterpret_cast<const bf16x8*>(&Ks[cur][sw(n * 16 + l15, kk * 64 + 16 * g)]);
                    sacc[n] = __builtin_amdgcn_mfma_f32_16x16x32_bf16(aq[kk], bk, sacc[n], 0, 0, 0);
                }
            }
            if (j == qt) {  // causal mask (only the diagonal tile needs it)
#pragma unroll
                for (int n = 0; n < 4; ++n)
#pragma unroll
                    for (int r = 0; r < 4; ++r)
                        if (n * 16 + l15 > wv * 16 + 4 * g + r) sacc[n][r] = -__builtin_inff();
            }

            // in-register online softmax (row = 16-lane group of C-layout)
            float p[4][4];
            float scf[4];
#pragma unroll
            for (int r = 0; r < 4; ++r) {
                float mx = fmaxf(fmaxf(sacc[0][r], sacc[1][r]), fmaxf(sacc[2][r], sacc[3][r]));
                mx = fmaxf(mx, __shfl_xor(mx, 1));
                mx = fmaxf(mx, __shfl_xor(mx, 2));
                mx = fmaxf(mx, __shfl_xor(mx, 4));
                mx = fmaxf(mx, __shfl_xor(mx, 8));
                float mn = fmaxf(m_st[r], mx);
                float s = __expf(m_st[r] - mn);
                float rs = 0.f;
#pragma unroll
                for (int n = 0; n < 4; ++n) { p[n][r] = __expf(sacc[n][r] - mn); rs += p[n][r]; }
                rs += __shfl_xor(rs, 1);
                rs += __shfl_xor(rs, 2);
                rs += __shfl_xor(rs, 4);
                rs += __shfl_xor(rs, 8);
                l_st[r] = l_st[r] * s + rs;
                m_st[r] = mn;
                scf[r] = s;
            }
#pragma unroll
            for (int n = 0; n < 4; ++n)
#pragma unroll
                for (int r = 0; r < 4; ++r) accO[n][r] *= scf[r];

            // P -> LDS (wave-private rows; no barrier needed before own-wave read)
#pragma unroll
            for (int n = 0; n < 4; ++n)
#pragma unroll
                for (int r = 0; r < 4; ++r)
                    Ps[sw(wv * 16 + 4 * g + r, (n * 16 + l15) * 2)] = f2bf(p[n][r]);

            if (pf) {   // write prefetched K/V into the other buffer
                int c0 = tid, c1 = tid + 256;
                *reinterpret_cast<uint4*>(&Ks[cur ^ 1][sw(c0 >> 3, (c0 & 7) * 16)]) = pk0;
                *reinterpret_cast<uint4*>(&Ks[cur ^ 1][sw(c1 >> 3, (c1 & 7) * 16)]) = pk1;
                *reinterpret_cast<uint4*>(&Vs[cur ^ 1][sw(c0 >> 3, (c0 & 7) * 16)]) = pv0;
                *reinterpret_cast<uint4*>(&Vs[cur ^ 1][sw(c1 >> 3, (c1 & 7) * 16)]) = pv1;
            }

            // O += P V
#pragma unroll
            for (int kk = 0; kk < 2; ++kk) {
                bf16x8 pa = *reinterpret_cast<const bf16x8*>(&Ps[sw(wv * 16 + l15, kk * 64 + 16 * g)]);
#pragma unroll
                for (int n = 0; n < 4; ++n) {
                    bf16x8 bv = *reinterpret_cast<const bf16x8*>(&Vs[cur][sw(n * 16 + l15, kk * 64 + 16 * g)]);
                    accO[n] = __builtin_amdgcn_mfma_f32_16x16x32_bf16(pa, bv, accO[n], 0, 0, 0);
                }
            }
            __syncthreads();   // protects: next stage overwrites buf cur^1? no — cur; and K/V reads done
        }

        // epilogue: O /= l, write Y row-major [t][1024]
#pragma unroll
        for (int r = 0; r < 4; ++r) {
            float inv = 1.0f / l_st[r];
            int row = qt * 64 + wv * 16 + 4 * g + r;
#pragma unroll
            for (int n = 0; n < 4; ++n)
                yw[(size_t)row * DM + h * DH + n * 16 + l15] = f2bf(accO[n][r] * inv);
        }
    }
}

// ---------------- O projection: out = Y @ Wo^T + bo (fp32). grid (8,32) ----------------
__global__ __launch_bounds__(256)
void oproj_kernel(const unsigned short* __restrict__ y,
                  const float* __restrict__ Wo, const float* __restrict__ bo,
                  float* __restrict__ out) {
    __shared__ unsigned short Al[128 * 64];
    __shared__ unsigned short Bl[128 * 64];

    const int tid = threadIdx.x;
    const int wv = tid >> 6, lane = tid & 63, g = lane >> 4, l15 = lane & 15;
    const int wr = (wv >> 1) * 64, wc = (wv & 1) * 64;
    const int row0 = blockIdx.y * 128, col0 = blockIdx.x * 128;

    f32x4 acc[4][4];
#pragma unroll
    for (int m = 0; m < 4; ++m)
#pragma unroll
        for (int n = 0; n < 4; ++n) acc[m][n] = (f32x4){0.f, 0.f, 0.f, 0.f};

    for (int kt = 0; kt < DM; kt += 64) {
#pragma unroll
        for (int i = 0; i < 4; ++i) {
            int idx = tid + i * 256;
            int r = idx >> 3, c8 = idx & 7;
            *reinterpret_cast<uint4*>(&Al[sw(r, c8 * 16)]) =
                *reinterpret_cast<const uint4*>(&y[(size_t)(row0 + r) * DM + kt + c8 * 8]);
            const float* pb = &Wo[(size_t)(col0 + r) * DM + kt + c8 * 8];
            float4 b0 = *reinterpret_cast<const float4*>(pb);
            float4 b1 = *reinterpret_cast<const float4*>(pb + 4);
            *reinterpret_cast<uint4*>(&Bl[sw(r, c8 * 16)]) = pack8(b0, b1);
        }
        __syncthreads();
#pragma unroll
        for (int kk = 0; kk < 2; ++kk) {
            bf16x8 a[4], b[4];
#pragma unroll
            for (int m = 0; m < 4; ++m)
                a[m] = *reinterpret_cast<const bf16x8*>(&Al[sw(wr + m * 16 + l15, kk * 64 + 16 * g)]);
#pragma unroll
            for (int n = 0; n < 4; ++n)
                b[n] = *reinterpret_cast<const bf16x8*>(&Bl[sw(wc + n * 16 + l15, kk * 64 + 16 * g)]);
#pragma unroll
            for (int m = 0; m < 4; ++m)
#pragma unroll
                for (int n = 0; n < 4; ++n)
                    acc[m][n] = __builtin_amdgcn_mfma_f32_16x16x32_bf16(a[m], b[n], acc[m][n], 0, 0, 0);
        }
        __syncthreads();
    }

#pragma unroll
    for (int n = 0; n < 4; ++n) {
        int col = col0 + wc + n * 16 + l15;
        float bval = bo[col];
#pragma unroll
        for (int m = 0; m < 4; ++m) {
            int rbase = row0 + wr + m * 16 + 4 * g;
#pragma unroll
            for (int r = 0; r < 4; ++r)
                out[(size_t)(rbase + r) * DM + col] = acc[m][n][r] + bval;
        }
    }
}

extern "C" void kernel_launch(void* const* d_in, const int* in_sizes, int n_in,
                              void* d_out, int out_size, void* d_ws, size_t ws_size,
                              hipStream_t stream) {
    const float* x  = (const float*)d_in[0];
    const float* Wq = (const float*)d_in[1];
    const float* bq = (const float*)d_in[2];
    const float* Wk = (const float*)d_in[3];
    const float* bk = (const float*)d_in[4];
    const float* Wv = (const float*)d_in[5];
    const float* bv = (const float*)d_in[6];
    const float* Wo = (const float*)d_in[7];
    const float* bo = (const float*)d_in[8];
    float* out = (float*)d_out;

    unsigned short* qw  = (unsigned short*)d_ws;
    unsigned short* kw  = qw + (size_t)TSZ * DM;
    unsigned short* vtw = kw + (size_t)TSZ * DM;
    unsigned short* yw  = vtw + (size_t)TSZ * DM;

    qkv_kernel<<<dim3(8, 32, 3), 256, 0, stream>>>(x, Wq, bq, Wk, bk, Wv, bv, qw, kw, vtw);
    attn_kernel<<<dim3(32, 16), 256, 0, stream>>>(qw, kw, vtw, yw);
    oproj_kernel<<<dim3(8, 32), 256, 0, stream>>>(yw, Wo, bo, out);
}

// Round 3
// 193.502 us; speedup vs baseline: 2.5540x; 1.8352x over previous
//
#include <hip/hip_runtime.h>

// Self-attention: x(1,4096,1024) fp32. bf16 MFMA pipeline.
// ws (40 MB): xb/yw alias (8MB) | wqb wkb wvb wob (2MB each) | qw kw vtw (8MB each)

#define TSZ 4096
#define DM  1024
#define NH  16
#define DH  64

typedef __bf16 bf16x8 __attribute__((ext_vector_type(8)));
typedef float  f32x4  __attribute__((ext_vector_type(4)));

__device__ __forceinline__ unsigned short f2bf(float x) {
    unsigned int u = __builtin_bit_cast(unsigned int, x);
    u += 0x7fffu + ((u >> 16) & 1u);
    return (unsigned short)(u >> 16);
}

__device__ __forceinline__ uint4 pack8(const float4 a, const float4 b) {
    uint4 r;
    r.x = (unsigned)f2bf(a.x) | ((unsigned)f2bf(a.y) << 16);
    r.y = (unsigned)f2bf(a.z) | ((unsigned)f2bf(a.w) << 16);
    r.z = (unsigned)f2bf(b.x) | ((unsigned)f2bf(b.y) << 16);
    r.w = (unsigned)f2bf(b.z) | ((unsigned)f2bf(b.w) << 16);
    return r;
}

// XOR-swizzled short-index into a [rows][64-short] tile (128B row stride).
__device__ __forceinline__ int sw(int row, int cb) {
    return row * 64 + ((cb ^ ((row & 7) << 4)) >> 1);
}

// async global->LDS, 16B per lane. lds base must be wave-uniform.
__device__ __forceinline__ void gll16(const unsigned short* g, unsigned short* l) {
    __builtin_amdgcn_global_load_lds((const __attribute__((address_space(1))) void*)g,
                                     (__attribute__((address_space(3))) void*)l,
                                     16, 0, 0);
}

// ---------------- fp32 -> bf16 prepass: x, Wq, Wk, Wv, Wo ----------------
#define XN  4194304u
#define WN  1048576u
__global__ __launch_bounds__(256)
void cvt_kernel(const float* __restrict__ x,  const float* __restrict__ wq,
                const float* __restrict__ wk, const float* __restrict__ wv,
                const float* __restrict__ wo,
                unsigned short* __restrict__ xb,  unsigned short* __restrict__ wqb,
                unsigned short* __restrict__ wkb, unsigned short* __restrict__ wvb,
                unsigned short* __restrict__ wob) {
    size_t e = ((size_t)blockIdx.x * 256 + threadIdx.x) * 8;
    const float* src; unsigned short* dst; size_t off;
    if (e < XN)               { src = x;  dst = xb;  off = e; }
    else if (e < XN + WN)     { src = wq; dst = wqb; off = e - XN; }
    else if (e < XN + 2 * WN) { src = wk; dst = wkb; off = e - XN - WN; }
    else if (e < XN + 3 * WN) { src = wv; dst = wvb; off = e - XN - 2 * WN; }
    else                      { src = wo; dst = wob; off = e - XN - 3 * WN; }
    float4 a = *reinterpret_cast<const float4*>(src + off);
    float4 b = *reinterpret_cast<const float4*>(src + off + 4);
    *reinterpret_cast<uint4*>(dst + off) = pack8(a, b);
}

// ---------------- QKV projection. 768 blocks, 256 thr. Tile 128x128, BK=64 ----------------
// XCD-chunked: XCD k owns output cols [384k, 384k+384) of the 3072-wide QKV concat
// (W slice 768KB bf16, L2-resident); x streams. z: 0=Q(scaled)->qw, 1=K->kw, 2=V->vtw (transposed).
__global__ __launch_bounds__(256)
void qkv_kernel(const unsigned short* __restrict__ xb,
                const unsigned short* __restrict__ wqb,
                const unsigned short* __restrict__ wkb,
                const unsigned short* __restrict__ wvb,
                const float* __restrict__ bq, const float* __restrict__ bk,
                const float* __restrict__ bv,
                unsigned short* __restrict__ qw,
                unsigned short* __restrict__ kw,
                unsigned short* __restrict__ vtw) {
    const int L = blockIdx.x;
    const int xcd = L & 7, i = L >> 3;   // 96 blocks per XCD
    const int lbx = i % 3, by = i / 3;
    const int bx = xcd * 3 + lbx;        // [0,24) col-tile of QKV concat
    const int z = bx >> 3;
    const int col0 = (bx & 7) * 128;
    const int row0 = by * 128;

    const unsigned short* W = (z == 0) ? wqb : (z == 1) ? wkb : wvb;
    const float* bias = (z == 0) ? bq : (z == 1) ? bk : bv;
    unsigned short* outp = (z == 0) ? qw : (z == 1) ? kw : vtw;
    const float scale = (z == 0) ? 0.125f : 1.0f;

    __shared__ unsigned short Al[128 * 64];
    __shared__ unsigned short Bl[128 * 64];

    const int tid = threadIdx.x;
    const int wid = tid >> 6, lane = tid & 63, g = lane >> 4, l15 = lane & 15;
    const int wr = (wid >> 1) * 64, wc = (wid & 1) * 64;

    f32x4 acc[4][4];
#pragma unroll
    for (int m = 0; m < 4; ++m)
#pragma unroll
        for (int n = 0; n < 4; ++n) acc[m][n] = (f32x4){0.f, 0.f, 0.f, 0.f};

    // staging geometry: chunk c = is*256+tid -> LDS linear c*16B; source col swizzled
    const int r_ = tid >> 3, c8_ = tid & 7;
    const int cbyte = (c8_ * 16) ^ ((r_ & 7) << 4);
    const unsigned short* ga0 = xb + (size_t)(row0 + r_) * DM + (cbyte >> 1);
    const unsigned short* gb0 = W + (size_t)(col0 + r_) * DM + (cbyte >> 1);
    unsigned short* la0 = &Al[(size_t)(wid * 64) * 8];
    unsigned short* lb0 = &Bl[(size_t)(wid * 64) * 8];

    for (int kt = 0; kt < DM; kt += 64) {
#pragma unroll
        for (int is = 0; is < 4; ++is) {  // each issue: 256 thr * 16B = 32 rows
            gll16(ga0 + (size_t)(is * 32) * DM + kt, la0 + (size_t)(is * 256) * 8);
            gll16(gb0 + (size_t)(is * 32) * DM + kt, lb0 + (size_t)(is * 256) * 8);
        }
        __syncthreads();
#pragma unroll
        for (int kk = 0; kk < 2; ++kk) {
            bf16x8 a[4], b[4];
#pragma unroll
            for (int m = 0; m < 4; ++m)
                a[m] = *reinterpret_cast<const bf16x8*>(&Al[sw(wr + m * 16 + l15, kk * 64 + 16 * g)]);
#pragma unroll
            for (int n = 0; n < 4; ++n)
                b[n] = *reinterpret_cast<const bf16x8*>(&Bl[sw(wc + n * 16 + l15, kk * 64 + 16 * g)]);
            if (z == 2) {
#pragma unroll
                for (int m = 0; m < 4; ++m)
#pragma unroll
                    for (int n = 0; n < 4; ++n)
                        acc[m][n] = __builtin_amdgcn_mfma_f32_16x16x32_bf16(b[n], a[m], acc[m][n], 0, 0, 0);
            } else {
#pragma unroll
                for (int m = 0; m < 4; ++m)
#pragma unroll
                    for (int n = 0; n < 4; ++n)
                        acc[m][n] = __builtin_amdgcn_mfma_f32_16x16x32_bf16(a[m], b[n], acc[m][n], 0, 0, 0);
            }
        }
        __syncthreads();
    }

    if (z == 2) {
        // swapped operands: M-dim = channel, N-dim = t. Write V^T [ch][t].
#pragma unroll
        for (int n = 0; n < 4; ++n)
#pragma unroll
            for (int r = 0; r < 4; ++r) {
                int ch = col0 + wc + n * 16 + 4 * g + r;
                float bval = bias[ch];
#pragma unroll
                for (int m = 0; m < 4; ++m) {
                    int t = row0 + wr + m * 16 + l15;
                    outp[(size_t)ch * TSZ + t] = f2bf(acc[m][n][r] + bval);
                }
            }
    } else {
#pragma unroll
        for (int n = 0; n < 4; ++n) {
            int col = col0 + wc + n * 16 + l15;
            float bval = bias[col];
            int hh = col >> 6, dd = col & 63;
#pragma unroll
            for (int m = 0; m < 4; ++m) {
                int rbase = row0 + wr + m * 16 + 4 * g;
#pragma unroll
                for (int r = 0; r < 4; ++r)
                    outp[((size_t)hh * TSZ + rbase + r) * DH + dd] = f2bf((acc[m][n][r] + bval) * scale);
            }
        }
    }
}

// ---------------- Flash attention, causal. grid (32, 16), block 256 ----------------
__global__ __launch_bounds__(256)
void attn_kernel(const unsigned short* __restrict__ qw,
                 const unsigned short* __restrict__ kw,
                 const unsigned short* __restrict__ vtw,
                 unsigned short* __restrict__ yw) {
    __shared__ unsigned short Qs[64 * 64];
    __shared__ unsigned short Ks[2][64 * 64];
    __shared__ unsigned short Vs[2][64 * 64];   // V^T tile: [d][t]
    __shared__ unsigned short Ps[64 * 64];

    const int h = blockIdx.y;
    const int tid = threadIdx.x;
    const int wid = tid >> 6, lane = tid & 63, g = lane >> 4, l15 = lane & 15;

    const unsigned short* qbase = qw + (size_t)h * TSZ * DH;
    const unsigned short* kbase = kw + (size_t)h * TSZ * DH;
    const unsigned short* vbase = vtw + (size_t)h * DH * TSZ;

    for (int half = 0; half < 2; ++half) {
        const int qt = (half == 0) ? (int)blockIdx.x : 63 - (int)blockIdx.x;

        {
            const unsigned short* qsrc = qbase + (size_t)qt * 64 * DH;
#pragma unroll
            for (int i = 0; i < 2; ++i) {
                int c = tid + i * 256;
                int r = c >> 3, c8 = c & 7;
                *reinterpret_cast<uint4*>(&Qs[sw(r, c8 * 16)]) =
                    *reinterpret_cast<const uint4*>(qsrc + c * 8);
                *reinterpret_cast<uint4*>(&Ks[0][sw(r, c8 * 16)]) =
                    *reinterpret_cast<const uint4*>(kbase + c * 8);
                *reinterpret_cast<uint4*>(&Vs[0][sw(r, c8 * 16)]) =
                    *reinterpret_cast<const uint4*>(vbase + (size_t)r * TSZ + c8 * 8);
            }
        }
        __syncthreads();

        bf16x8 aq[2];
        aq[0] = *reinterpret_cast<const bf16x8*>(&Qs[sw(wid * 16 + l15, 16 * g)]);
        aq[1] = *reinterpret_cast<const bf16x8*>(&Qs[sw(wid * 16 + l15, 64 + 16 * g)]);

        float m_st[4], l_st[4];
        f32x4 accO[4];
#pragma unroll
        for (int r = 0; r < 4; ++r) { m_st[r] = -__builtin_inff(); l_st[r] = 0.f; }
#pragma unroll
        for (int n = 0; n < 4; ++n) accO[n] = (f32x4){0.f, 0.f, 0.f, 0.f};

        for (int j = 0; j <= qt; ++j) {
            const int cur = j & 1;
            const bool pf = (j < qt);
            uint4 pk0, pk1, pv0, pv1;
            if (pf) {
                const unsigned short* ks = kbase + (size_t)(j + 1) * 64 * DH;
                const unsigned short* vs = vbase + (size_t)(j + 1) * 64;
                int c0 = tid, c1 = tid + 256;
                pk0 = *reinterpret_cast<const uint4*>(ks + c0 * 8);
                pk1 = *reinterpret_cast<const uint4*>(ks + c1 * 8);
                pv0 = *reinterpret_cast<const uint4*>(vs + (size_t)(c0 >> 3) * TSZ + (c0 & 7) * 8);
                pv1 = *reinterpret_cast<const uint4*>(vs + (size_t)(c1 >> 3) * TSZ + (c1 & 7) * 8);
            }

            f32x4 sacc[4];
#pragma unroll
            for (int n = 0; n < 4; ++n) sacc[n] = (f32x4){0.f, 0.f, 0.f, 0.f};
#pragma unroll
            for (int kk = 0; kk < 2; ++kk) {
#pragma unroll
                for (int n = 0; n < 4; ++n) {
                    bf16x8 bk = *reinterpret_cast<const bf16x8*>(&Ks[cur][sw(n * 16 + l15, kk * 64 + 16 * g)]);
                    sacc[n] = __builtin_amdgcn_mfma_f32_16x16x32_bf16(aq[kk], bk, sacc[n], 0, 0, 0);
                }
            }
            if (j == qt) {
#pragma unroll
                for (int n = 0; n < 4; ++n)
#pragma unroll
                    for (int r = 0; r < 4; ++r)
                        if (n * 16 + l15 > wid * 16 + 4 * g + r) sacc[n][r] = -__builtin_inff();
            }

            float p[4][4];
            float scf[4];
#pragma unroll
            for (int r = 0; r < 4; ++r) {
                float mx = fmaxf(fmaxf(sacc[0][r], sacc[1][r]), fmaxf(sacc[2][r], sacc[3][r]));
                mx = fmaxf(mx, __shfl_xor(mx, 1));
                mx = fmaxf(mx, __shfl_xor(mx, 2));
                mx = fmaxf(mx, __shfl_xor(mx, 4));
                mx = fmaxf(mx, __shfl_xor(mx, 8));
                float mn = fmaxf(m_st[r], mx);
                float s = __expf(m_st[r] - mn);
                float rs = 0.f;
#pragma unroll
                for (int n = 0; n < 4; ++n) { p[n][r] = __expf(sacc[n][r] - mn); rs += p[n][r]; }
                rs += __shfl_xor(rs, 1);
                rs += __shfl_xor(rs, 2);
                rs += __shfl_xor(rs, 4);
                rs += __shfl_xor(rs, 8);
                l_st[r] = l_st[r] * s + rs;
                m_st[r] = mn;
                scf[r] = s;
            }
#pragma unroll
            for (int n = 0; n < 4; ++n)
#pragma unroll
                for (int r = 0; r < 4; ++r) accO[n][r] *= scf[r];

#pragma unroll
            for (int n = 0; n < 4; ++n)
#pragma unroll
                for (int r = 0; r < 4; ++r)
                    Ps[sw(wid * 16 + 4 * g + r, (n * 16 + l15) * 2)] = f2bf(p[n][r]);

            if (pf) {
                int c0 = tid, c1 = tid + 256;
                *reinterpret_cast<uint4*>(&Ks[cur ^ 1][sw(c0 >> 3, (c0 & 7) * 16)]) = pk0;
                *reinterpret_cast<uint4*>(&Ks[cur ^ 1][sw(c1 >> 3, (c1 & 7) * 16)]) = pk1;
                *reinterpret_cast<uint4*>(&Vs[cur ^ 1][sw(c0 >> 3, (c0 & 7) * 16)]) = pv0;
                *reinterpret_cast<uint4*>(&Vs[cur ^ 1][sw(c1 >> 3, (c1 & 7) * 16)]) = pv1;
            }

#pragma unroll
            for (int kk = 0; kk < 2; ++kk) {
                bf16x8 pa = *reinterpret_cast<const bf16x8*>(&Ps[sw(wid * 16 + l15, kk * 64 + 16 * g)]);
#pragma unroll
                for (int n = 0; n < 4; ++n) {
                    bf16x8 bv = *reinterpret_cast<const bf16x8*>(&Vs[cur][sw(n * 16 + l15, kk * 64 + 16 * g)]);
                    accO[n] = __builtin_amdgcn_mfma_f32_16x16x32_bf16(pa, bv, accO[n], 0, 0, 0);
                }
            }
            __syncthreads();
        }

#pragma unroll
        for (int r = 0; r < 4; ++r) {
            float inv = 1.0f / l_st[r];
            int row = qt * 64 + wid * 16 + 4 * g + r;
#pragma unroll
            for (int n = 0; n < 4; ++n)
                yw[(size_t)row * DM + h * DH + n * 16 + l15] = f2bf(accO[n][r] * inv);
        }
    }
}

// ---------------- O projection: out = Y @ Wo^T + bo (fp32). 256 blocks ----------------
// XCD-chunked by row-panels: XCD k owns rows [512k, 512k+512); Wo (2MB) L2-resident.
__global__ __launch_bounds__(256)
void oproj_kernel(const unsigned short* __restrict__ y,
                  const unsigned short* __restrict__ wob,
                  const float* __restrict__ bo,
                  float* __restrict__ out) {
    const int L = blockIdx.x;
    const int xcd = L & 7, i = L >> 3;   // 32 per XCD
    const int bx = i & 7, lby = i >> 3;  // bx fastest: 8 blocks share a Y panel
    const int by = xcd * 4 + lby;
    const int row0 = by * 128, col0 = bx * 128;

    __shared__ unsigned short Al[128 * 64];
    __shared__ unsigned short Bl[128 * 64];

    const int tid = threadIdx.x;
    const int wid = tid >> 6, lane = tid & 63, g = lane >> 4, l15 = lane & 15;
    const int wr = (wid >> 1) * 64, wc = (wid & 1) * 64;

    f32x4 acc[4][4];
#pragma unroll
    for (int m = 0; m < 4; ++m)
#pragma unroll
        for (int n = 0; n < 4; ++n) acc[m][n] = (f32x4){0.f, 0.f, 0.f, 0.f};

    const int r_ = tid >> 3, c8_ = tid & 7;
    const int cbyte = (c8_ * 16) ^ ((r_ & 7) << 4);
    const unsigned short* ga0 = y + (size_t)(row0 + r_) * DM + (cbyte >> 1);
    const unsigned short* gb0 = wob + (size_t)(col0 + r_) * DM + (cbyte >> 1);
    unsigned short* la0 = &Al[(size_t)(wid * 64) * 8];
    unsigned short* lb0 = &Bl[(size_t)(wid * 64) * 8];

    for (int kt = 0; kt < DM; kt += 64) {
#pragma unroll
        for (int is = 0; is < 4; ++is) {
            gll16(ga0 + (size_t)(is * 32) * DM + kt, la0 + (size_t)(is * 256) * 8);
            gll16(gb0 + (size_t)(is * 32) * DM + kt, lb0 + (size_t)(is * 256) * 8);
        }
        __syncthreads();
#pragma unroll
        for (int kk = 0; kk < 2; ++kk) {
            bf16x8 a[4], b[4];
#pragma unroll
            for (int m = 0; m < 4; ++m)
                a[m] = *reinterpret_cast<const bf16x8*>(&Al[sw(wr + m * 16 + l15, kk * 64 + 16 * g)]);
#pragma unroll
            for (int n = 0; n < 4; ++n)
                b[n] = *reinterpret_cast<const bf16x8*>(&Bl[sw(wc + n * 16 + l15, kk * 64 + 16 * g)]);
#pragma unroll
            for (int m = 0; m < 4; ++m)
#pragma unroll
                for (int n = 0; n < 4; ++n)
                    acc[m][n] = __builtin_amdgcn_mfma_f32_16x16x32_bf16(a[m], b[n], acc[m][n], 0, 0, 0);
        }
        __syncthreads();
    }

#pragma unroll
    for (int n = 0; n < 4; ++n) {
        int col = col0 + wc + n * 16 + l15;
        float bval = bo[col];
#pragma unroll
        for (int m = 0; m < 4; ++m) {
            int rbase = row0 + wr + m * 16 + 4 * g;
#pragma unroll
            for (int r = 0; r < 4; ++r)
                out[(size_t)(rbase + r) * DM + col] = acc[m][n][r] + bval;
        }
    }
}

extern "C" void kernel_launch(void* const* d_in, const int* in_sizes, int n_in,
                              void* d_out, int out_size, void* d_ws, size_t ws_size,
                              hipStream_t stream) {
    const float* x  = (const float*)d_in[0];
    const float* Wq = (const float*)d_in[1];
    const float* bq = (const float*)d_in[2];
    const float* Wk = (const float*)d_in[3];
    const float* bk = (const float*)d_in[4];
    const float* Wv = (const float*)d_in[5];
    const float* bv = (const float*)d_in[6];
    const float* Wo = (const float*)d_in[7];
    const float* bo = (const float*)d_in[8];
    float* out = (float*)d_out;

    unsigned short* xb  = (unsigned short*)d_ws;   // 8 MB (aliased as yw after qkv)
    unsigned short* wqb = xb + 4194304;
    unsigned short* wkb = wqb + 1048576;
    unsigned short* wvb = wkb + 1048576;
    unsigned short* wob = wvb + 1048576;
    unsigned short* qw  = wob + 1048576;
    unsigned short* kw  = qw + 4194304;
    unsigned short* vtw = kw + 4194304;
    unsigned short* yw  = xb;                       // alias: xb dead after qkv

    cvt_kernel<<<4096, 256, 0, stream>>>(x, Wq, Wk, Wv, Wo, xb, wqb, wkb, wvb, wob);
    qkv_kernel<<<768, 256, 0, stream>>>(xb, wqb, wkb, wvb, bq, bk, bv, qw, kw, vtw);
    attn_kernel<<<dim3(32, 16), 256, 0, stream>>>(qw, kw, vtw, yw);
    oproj_kernel<<<256, 256, 0, stream>>>(yw, wob, bo, out);
}